// Round 8
// baseline (311.041 us; speedup 1.0000x reference)
//
#include <hip/hip_runtime.h>
#include <stdint.h>

#define NN 8192
#define MM 16
#define FN 128
#define HH 512

typedef unsigned short u16;
typedef unsigned int u32;
typedef __bf16 bf16;
typedef __bf16 bf16x8 __attribute__((ext_vector_type(8)));
typedef float f32x4 __attribute__((ext_vector_type(4)));

// async global->LDS, 16B/lane; LDS dest = wave-uniform base + lane*16
__device__ __forceinline__ void gld_lds16(const u16* g, u16* l) {
  __builtin_amdgcn_global_load_lds(
      (const __attribute__((address_space(1))) void*)g,
      (__attribute__((address_space(3))) void*)l, 16, 0, 0);
}

// ---- dtype probes (per-wave; ~2 cached loads + ballot) ----
__device__ __forceinline__ int probe_f32(const u16* w) {
  int lane = threadIdx.x & 63;
  int e = (w[2 * lane] >> 7) & 0xFF;
  unsigned long long m = __ballot(!(e == 0 || (e >= 90 && e <= 140)));
  return __popcll(m) >= 8;
}
__device__ __forceinline__ int probe_i64(const u32* w) {
  int lane = threadIdx.x & 63;
  unsigned long long m = __ballot(lane < 32 && w[2 * lane + 1] != 0);
  return m == 0;
}

__device__ __forceinline__ bf16 cvt_elem(const void* p, size_t i, int f32) {
  return f32 ? (bf16)((const float*)p)[i] : ((const bf16*)p)[i];
}

// ---- prep: TWc = (Wemb@W1)^T  (blocks 0..63, 32k x 32n tiles)
//            bvec = bemb@W1     (blocks 64..65, f32)
__global__ __launch_bounds__(256) void prep_kernel(
    const u16* __restrict__ node, const void* __restrict__ Wemb,
    const void* __restrict__ bemb, const void* __restrict__ W1,
    u16* __restrict__ TWc, float* __restrict__ bvec) {
  const int f32in = probe_f32(node);
  const int bid = blockIdx.x, tid = threadIdx.x;
  if (bid < 64) {
    // tile: k0 = (bid>>4)*32 (of 128), n0 = (bid&15)*32 (of 512)
    const int k0 = (bid >> 4) * 32, n0 = (bid & 15) * 32;
    __shared__ u16 Ws[32 * 256];   // Wemb[k0+k][mc+m]
    __shared__ u16 W1s[256 * 32];  // W1[mc+m][n0+n]
    const int k = tid >> 3, nb = (tid & 7) * 4;
    float acc[4] = {0.f, 0.f, 0.f, 0.f};
    for (int mc = 0; mc < HH; mc += 256) {
      {
        const int row = tid >> 3, seg = (tid & 7) * 32;
#pragma unroll 8
        for (int i = 0; i < 32; ++i) {
          bf16 v = cvt_elem(Wemb, (size_t)(k0 + row) * HH + mc + seg + i, f32in);
          Ws[row * 256 + seg + i] = *(u16*)&v;
        }
#pragma unroll 8
        for (int i = 0; i < 32; ++i) {
          bf16 v = cvt_elem(W1, (size_t)(mc + tid) * HH + n0 + i, f32in);
          W1s[tid * 32 + i] = *(u16*)&v;
        }
      }
      __syncthreads();
#pragma unroll 8
      for (int m = 0; m < 256; ++m) {
        float a = (float)*(const bf16*)&Ws[k * 256 + m];
        const bf16* w4 = (const bf16*)&W1s[m * 32 + nb];
#pragma unroll
        for (int j = 0; j < 4; ++j) acc[j] += a * (float)w4[j];
      }
      __syncthreads();
    }
#pragma unroll
    for (int j = 0; j < 4; ++j) {
      bf16 o = (bf16)acc[j];
      TWc[(size_t)(n0 + nb + j) * FN + k0 + k] = *(u16*)&o;
    }
  } else {
    const int n = (bid - 64) * 256 + tid;  // 0..511
    float acc = 0.f;
#pragma unroll 8
    for (int m = 0; m < HH; ++m) {
      float b = (float)cvt_elem(bemb, m, f32in);
      float w = (float)cvt_elem(W1, (size_t)m * HH + n, f32in);
      acc += b * w;
    }
    bvec[n] = acc;
  }
}

// ---- transpose one 32x32 tile of W (512 x 512) -> T (512 x 512) ----
__device__ __forceinline__ void transpose_tile(const void* __restrict__ W,
                                               u16* __restrict__ T, int tt,
                                               int f32in, u16* sm) {
  const int k0 = (tt >> 4) * 32, n0 = (tt & 15) * 32;
  const int tx = threadIdx.x & 31, ty = threadIdx.x >> 5;  // ty 0..7
#pragma unroll
  for (int r = ty; r < 32; r += 8) {
    bf16 v = cvt_elem(W, (size_t)(k0 + r) * HH + n0 + tx, f32in);
    sm[r * 33 + tx] = *(u16*)&v;
  }
  __syncthreads();
#pragma unroll
  for (int r = ty; r < 32; r += 8)
    T[(size_t)(n0 + r) * HH + k0 + tx] = sm[tx * 33 + r];
}

// ---- GEMM tile: C[rtile*64..+64][ctile*128..+128] = A @ Bt^T (+ biasf)
// 256 thr / 4 waves (2x2), wave 32x64 (2x4 accs of 16x16x32), BK=64,
// gld_lds + XOR swizzle (LDS chunk (row,cc) holds k-chunk gc = cc^(row&7)).
// R5-R7-verified: correct, 0 bank conflicts. Always writes bf16.
__device__ __forceinline__ void gemm_tile(const void* __restrict__ A, int K,
                                          int af32, const u16* __restrict__ Bt,
                                          const float* __restrict__ biasf,
                                          int rtile, int ctile,
                                          u16* __restrict__ C, u16* As,
                                          u16* Bs) {
  const int tid = threadIdx.x;
  const int wave = tid >> 6, lane = tid & 63;
  const int wr = wave >> 1, wc = wave & 1;
  const int quad = lane >> 4, l16 = lane & 15;
  f32x4 acc[2][4] = {};

  int arow[2], agc[2], brow[4], bgc[4];
#pragma unroll
  for (int i = 0; i < 2; ++i) {
    int c = i * 256 + tid;
    arow[i] = c >> 3;
    agc[i] = (c & 7) ^ (arow[i] & 7);
  }
#pragma unroll
  for (int i = 0; i < 4; ++i) {
    int c = i * 256 + tid;
    brow[i] = c >> 3;
    bgc[i] = (c & 7) ^ (brow[i] & 7);
  }
  u16* AsW = As + wave * 512;  // wave-uniform LDS bases (chunk c -> c*16 B)
  u16* BsW = Bs + wave * 512;

  for (int k0 = 0; k0 < K; k0 += 64) {
    __syncthreads();  // prev iter's ds_reads done
    if (af32) {
      const float* Af = (const float*)A;
      bf16x8 v[2];
#pragma unroll
      for (int i = 0; i < 2; ++i) {
        const float* p = &Af[(size_t)(rtile * 64 + arow[i]) * K + k0 + agc[i] * 8];
        f32x4 x0 = *(const f32x4*)p, x1 = *(const f32x4*)(p + 4);
#pragma unroll
        for (int t = 0; t < 4; ++t) {
          v[i][t] = (bf16)x0[t];
          v[i][4 + t] = (bf16)x1[t];
        }
      }
#pragma unroll
      for (int i = 0; i < 2; ++i) *(bf16x8*)&As[(i * 256 + tid) * 8] = v[i];
    } else {
      const u16* Ab = (const u16*)A;
#pragma unroll
      for (int i = 0; i < 2; ++i)
        gld_lds16(&Ab[(size_t)(rtile * 64 + arow[i]) * K + k0 + agc[i] * 8],
                  AsW + i * 2048);
    }
#pragma unroll
    for (int i = 0; i < 4; ++i)
      gld_lds16(&Bt[(size_t)(ctile * 128 + brow[i]) * K + k0 + bgc[i] * 8],
                BsW + i * 2048);
    __syncthreads();  // drains vmcnt (DMA complete)
#pragma unroll
    for (int h = 0; h < 2; ++h) {
      bf16x8 af[2], bfr[4];
#pragma unroll
      for (int i = 0; i < 2; ++i) {
        int r = wr * 32 + i * 16 + l16;
        int cc = (h * 4 + quad) ^ (r & 7);
        af[i] = *(const bf16x8*)&As[r * 64 + cc * 8];
      }
#pragma unroll
      for (int j = 0; j < 4; ++j) {
        int n = wc * 64 + j * 16 + l16;
        int cc = (h * 4 + quad) ^ (n & 7);
        bfr[j] = *(const bf16x8*)&Bs[n * 64 + cc * 8];
      }
#pragma unroll
      for (int i = 0; i < 2; ++i)
#pragma unroll
        for (int j = 0; j < 4; ++j)
          acc[i][j] = __builtin_amdgcn_mfma_f32_16x16x32_bf16(af[i], bfr[j],
                                                              acc[i][j], 0, 0, 0);
    }
  }

  // C/D layout: col = lane&15, row = quad*4 + reg (m89/m91)
  const int crow0 = rtile * 64 + wr * 32 + quad * 4;
  const int ccol0 = ctile * 128 + wc * 64 + l16;
#pragma unroll
  for (int j = 0; j < 4; ++j) {
    const int col = ccol0 + j * 16;
    const float bv = biasf ? biasf[col] : 0.f;
#pragma unroll
    for (int i = 0; i < 2; ++i)
#pragma unroll
      for (int r = 0; r < 4; ++r) {
        bf16 o = (bf16)(acc[i][j][r] + bv);
        C[(size_t)(crow0 + i * 16 + r) * HH + col] = *(u16*)&o;
      }
  }
}

// ---- G1: t = node@TWc^T + bvec (blocks 0..511) + deg (512..543) +
//      TW2/TW3 transposes (544..1055). Extras independent of GEMM output.
__global__ __launch_bounds__(256) void g1_kernel(
    const u16* __restrict__ node, const u32* __restrict__ idxw,
    const void* __restrict__ W2, const void* __restrict__ W3,
    const u16* __restrict__ TWc, const float* __restrict__ bvec,
    float* __restrict__ dis, u16* __restrict__ TW2, u16* __restrict__ TW3,
    u16* __restrict__ xout) {
  __shared__ __align__(16) u16 As[64 * 64];
  __shared__ __align__(16) u16 Bs[128 * 64];
  const int bid = blockIdx.x, tid = threadIdx.x;
  if (bid < 512) {
    const int af32 = probe_f32(node);
    gemm_tile(node, FN, af32, TWc, bvec, bid >> 2, bid & 3, xout, As, Bs);
  } else if (bid < 544) {
    const int i64 = probe_i64(idxw);
    const int* idx = (const int*)idxw;
    const int i = (bid - 512) * 256 + tid;
    int c = 1;
#pragma unroll
    for (int e = 0; e < MM; ++e) c += (idx[(i * MM + e) << i64] >= 0) ? 1 : 0;
    dis[i] = rsqrtf((float)c);
  } else {
    const int f32in = probe_f32(node);
    const int t = bid - 544;  // 0..511
    transpose_tile(t < 256 ? W2 : W3, t < 256 ? TW2 : TW3, t & 255, f32in, As);
  }
}

// ---- mid GEMM: t = x @ W^T (no epilogue; bias/relu live in the next agg)
__global__ __launch_bounds__(256) void gemm_mid(const u16* __restrict__ A,
                                                const u16* __restrict__ Bt,
                                                u16* __restrict__ C) {
  __shared__ __align__(16) u16 As[64 * 64];
  __shared__ __align__(16) u16 Bs[128 * 64];
  gemm_tile(A, HH, 0, Bt, nullptr, blockIdx.x, blockIdx.y, C, As, Bs);
}

// ---- agg + epilogue: y[i,:] = act( d[i]*( d[i]*t[i,:] + sum d[j]*t[j,:] ) + b )
// XCD-pinned column strips (R7): strip s read only by blocks with
// blockIdx%8 in {2s,2s+1} -> 2 MB of t resident per XCD-pair L2.
template <bool RELU, bool FINAL>
__global__ __launch_bounds__(256) void agg_kernel(
    const u16* __restrict__ t, const u32* __restrict__ idxw,
    const float* __restrict__ dis, const void* __restrict__ bias,
    const u16* __restrict__ nodeprobe, void* __restrict__ y) {
  const int i64 = probe_i64(idxw);
  const int f32io = probe_f32(nodeprobe);
  const int* idx = (const int*)idxw;
  const int b = blockIdx.x;
  const int strip = (b & 7) >> 1;          // 0..3, pinned to XCD pair
  const int grp = (b >> 3) * 2 + (b & 1);  // 0..511 node group
  const int wave = threadIdx.x >> 6, lane = threadIdx.x & 63;
  const int node = grp * 16 + wave * 4 + (lane >> 4);
  const int c0 = strip * 128 + (lane & 15) * 8;
  const float wi = dis[node];
  float acc[8];
  bf16x8 xs = *(const bf16x8*)&t[(size_t)node * HH + c0];
#pragma unroll
  for (int k = 0; k < 8; ++k) acc[k] = wi * wi * (float)xs[k];
#pragma unroll
  for (int e = 0; e < MM; ++e) {
    const int j = idx[(node * MM + e) << i64];
    if (j >= 0) {
      const float w = wi * dis[j];
      bf16x8 v = *(const bf16x8*)&t[(size_t)j * HH + c0];
#pragma unroll
      for (int k = 0; k < 8; ++k) acc[k] += w * (float)v[k];
    }
  }
  // epilogue: + bias, optional relu, write (final: maybe f32)
  float bv[8];
  if (f32io) {
    f32x4 b0 = *(const f32x4*)&((const float*)bias)[c0];
    f32x4 b1 = *(const f32x4*)&((const float*)bias)[c0 + 4];
#pragma unroll
    for (int k = 0; k < 4; ++k) { bv[k] = b0[k]; bv[4 + k] = b1[k]; }
  } else {
    bf16x8 bb = *(const bf16x8*)&((const u16*)bias)[c0];
#pragma unroll
    for (int k = 0; k < 8; ++k) bv[k] = (float)bb[k];
  }
#pragma unroll
  for (int k = 0; k < 8; ++k) {
    acc[k] += bv[k];
    if (RELU) acc[k] = fmaxf(acc[k], 0.f);
  }
  if (FINAL && f32io) {
    float* O = (float*)y;
    f32x4 o0, o1;
#pragma unroll
    for (int k = 0; k < 4; ++k) { o0[k] = acc[k]; o1[k] = acc[4 + k]; }
    *(f32x4*)&O[(size_t)node * HH + c0] = o0;
    *(f32x4*)&O[(size_t)node * HH + c0 + 4] = o1;
  } else {
    bf16x8 o;
#pragma unroll
    for (int k = 0; k < 8; ++k) o[k] = (bf16)acc[k];
    *(bf16x8*)&((u16*)y)[(size_t)node * HH + c0] = o;
  }
}

extern "C" void kernel_launch(void* const* d_in, const int* in_sizes, int n_in,
                              void* d_out, int out_size, void* d_ws, size_t ws_size,
                              hipStream_t stream) {
  const u16* node = (const u16*)d_in[0];
  const u32* idxw = (const u32*)d_in[1];
  const void* Wemb = d_in[2];
  const void* bemb = d_in[3];
  const void* W1 = d_in[4];
  const void* b1 = d_in[5];
  const void* W2 = d_in[6];
  const void* b2 = d_in[7];
  const void* W3 = d_in[8];
  const void* b3 = d_in[9];

  char* p = (char*)d_ws;
  float* dis = (float*)p;   p += NN * sizeof(float);
  float* bvec = (float*)p;  p += HH * sizeof(float);
  u16* TWc = (u16*)p;       p += (size_t)HH * FN * 2;
  u16* TW2 = (u16*)p;       p += (size_t)HH * HH * 2;
  u16* TW3 = (u16*)p;       p += (size_t)HH * HH * 2;
  u16* xA = (u16*)p;        // 8 MB GEMM-out buffer
  u16* xO = (u16*)d_out;    // d_out doubles as bf16 ping buffer

  prep_kernel<<<66, 256, 0, stream>>>(node, Wemb, bemb, W1, TWc, bvec);
  g1_kernel<<<1056, 256, 0, stream>>>(node, idxw, W2, W3, TWc, bvec, dis, TW2,
                                      TW3, xA);
  agg_kernel<true, false>
      <<<NN / 4, 256, 0, stream>>>(xA, idxw, dis, b1, node, xO);
  gemm_mid<<<dim3(128, 4), 256, 0, stream>>>(xO, TW2, xA);
  agg_kernel<true, false>
      <<<NN / 4, 256, 0, stream>>>(xA, idxw, dis, b2, node, xO);
  gemm_mid<<<dim3(128, 4), 256, 0, stream>>>(xO, TW3, xA);
  agg_kernel<false, true>
      <<<NN / 4, 256, 0, stream>>>(xA, idxw, dis, b3, node, d_out);
}

// Round 9
// 165.319 us; speedup vs baseline: 1.8815x; 1.8815x over previous
//
#include <hip/hip_runtime.h>
#include <stdint.h>

#define NN 8192
#define MM 16
#define FN 128
#define HH 512

typedef unsigned short u16;
typedef unsigned int u32;
typedef __bf16 bf16;
typedef __bf16 bf16x8 __attribute__((ext_vector_type(8)));
typedef float f32x4 __attribute__((ext_vector_type(4)));

// async global->LDS, 16B/lane; LDS dest = wave-uniform base + lane*16
__device__ __forceinline__ void gld_lds16(const u16* g, u16* l) {
  __builtin_amdgcn_global_load_lds(
      (const __attribute__((address_space(1))) void*)g,
      (__attribute__((address_space(3))) void*)l, 16, 0, 0);
}

// ---- dtype probes (per-wave; ~2 cached loads + ballot) ----
__device__ __forceinline__ int probe_f32(const u16* w) {
  int lane = threadIdx.x & 63;
  int e = (w[2 * lane] >> 7) & 0xFF;
  unsigned long long m = __ballot(!(e == 0 || (e >= 90 && e <= 140)));
  return __popcll(m) >= 8;
}
__device__ __forceinline__ int probe_i64(const u32* w) {
  int lane = threadIdx.x & 63;
  unsigned long long m = __ballot(lane < 32 && w[2 * lane + 1] != 0);
  return m == 0;
}

__device__ __forceinline__ bf16 cvt_elem(const void* p, size_t i, int f32) {
  return f32 ? (bf16)((const float*)p)[i] : ((const bf16*)p)[i];
}

// ---- transpose one 32x32 tile of W (512 x 512) -> T (512 x 512) ----
__device__ __forceinline__ void transpose_tile(const void* __restrict__ W,
                                               u16* __restrict__ T, int tt,
                                               int f32in, u16* sm) {
  const int k0 = (tt >> 4) * 32, n0 = (tt & 15) * 32;
  const int tx = threadIdx.x & 31, ty = threadIdx.x >> 5;  // ty 0..7
#pragma unroll
  for (int r = ty; r < 32; r += 8) {
    bf16 v = cvt_elem(W, (size_t)(k0 + r) * HH + n0 + tx, f32in);
    sm[r * 33 + tx] = *(u16*)&v;
  }
  __syncthreads();
#pragma unroll
  for (int r = ty; r < 32; r += 8)
    T[(size_t)(n0 + r) * HH + k0 + tx] = sm[tx * 33 + r];
}

// ---- prep1: TW1/TW2/TW3 transposes (0..767) + deg (768..799) +
//             WembB bf16 copy (800..831, only matters when input is fp32)
__global__ __launch_bounds__(256) void prep1_kernel(
    const u16* __restrict__ node, const u32* __restrict__ idxw,
    const void* __restrict__ Wemb, const void* __restrict__ W1,
    const void* __restrict__ W2, const void* __restrict__ W3,
    float* __restrict__ dis, u16* __restrict__ TW1, u16* __restrict__ TW2,
    u16* __restrict__ TW3, u16* __restrict__ WembB) {
  __shared__ u16 sm[32 * 33];
  const int bid = blockIdx.x, tid = threadIdx.x;
  if (bid < 768) {
    const int f32in = probe_f32(node);
    const int q = bid >> 8, tt = bid & 255;
    transpose_tile(q == 0 ? W1 : q == 1 ? W2 : W3,
                   q == 0 ? TW1 : q == 1 ? TW2 : TW3, tt, f32in, sm);
  } else if (bid < 800) {
    const int i64 = probe_i64(idxw);
    const int* idx = (const int*)idxw;
    const int i = (bid - 768) * 256 + tid;
    int c = 1;
#pragma unroll
    for (int e = 0; e < MM; ++e) c += (idx[(i * MM + e) << i64] >= 0) ? 1 : 0;
    dis[i] = rsqrtf((float)c);
  } else {
    const int f32in = probe_f32(node);
    const size_t g = ((size_t)(bid - 800) * 256 + tid) * 8;  // 8 elems/thread
    bf16x8 o;
    if (f32in) {
      f32x4 a = *(const f32x4*)&((const float*)Wemb)[g];
      f32x4 b = *(const f32x4*)&((const float*)Wemb)[g + 4];
#pragma unroll
      for (int t = 0; t < 4; ++t) { o[t] = (bf16)a[t]; o[4 + t] = (bf16)b[t]; }
    } else {
      o = *(const bf16x8*)&((const u16*)Wemb)[g];
    }
    *(bf16x8*)&WembB[g] = o;
  }
}

// ---- GEMM tile: C[rtile*64..+64][ctile*128..+128] = A @ Bt^T (+ biasf)
// 256 thr / 4 waves (2x2), wave 32x64 (2x4 accs of 16x16x32), BK=64,
// gld_lds + XOR swizzle (LDS chunk (row,cc) holds k-chunk gc = cc^(row&7)).
// R5-R8-verified: correct, 0 bank conflicts. Writes bf16, row stride cstride.
__device__ __forceinline__ void gemm_tile(const void* __restrict__ A, int K,
                                          int af32, const u16* __restrict__ Bt,
                                          const float* __restrict__ biasf,
                                          int rtile, int ctile,
                                          u16* __restrict__ C, int cstride,
                                          u16* As, u16* Bs) {
  const int tid = threadIdx.x;
  const int wave = tid >> 6, lane = tid & 63;
  const int wr = wave >> 1, wc = wave & 1;
  const int quad = lane >> 4, l16 = lane & 15;
  f32x4 acc[2][4] = {};

  int arow[2], agc[2], brow[4], bgc[4];
#pragma unroll
  for (int i = 0; i < 2; ++i) {
    int c = i * 256 + tid;
    arow[i] = c >> 3;
    agc[i] = (c & 7) ^ (arow[i] & 7);
  }
#pragma unroll
  for (int i = 0; i < 4; ++i) {
    int c = i * 256 + tid;
    brow[i] = c >> 3;
    bgc[i] = (c & 7) ^ (brow[i] & 7);
  }
  u16* AsW = As + wave * 512;  // wave-uniform LDS bases (chunk c -> c*16 B)
  u16* BsW = Bs + wave * 512;

  for (int k0 = 0; k0 < K; k0 += 64) {
    __syncthreads();  // prev iter's ds_reads done
    if (af32) {
      const float* Af = (const float*)A;
      bf16x8 v[2];
#pragma unroll
      for (int i = 0; i < 2; ++i) {
        const float* p = &Af[(size_t)(rtile * 64 + arow[i]) * K + k0 + agc[i] * 8];
        f32x4 x0 = *(const f32x4*)p, x1 = *(const f32x4*)(p + 4);
#pragma unroll
        for (int t = 0; t < 4; ++t) {
          v[i][t] = (bf16)x0[t];
          v[i][4 + t] = (bf16)x1[t];
        }
      }
#pragma unroll
      for (int i = 0; i < 2; ++i) *(bf16x8*)&As[(i * 256 + tid) * 8] = v[i];
    } else {
      const u16* Ab = (const u16*)A;
#pragma unroll
      for (int i = 0; i < 2; ++i)
        gld_lds16(&Ab[(size_t)(rtile * 64 + arow[i]) * K + k0 + agc[i] * 8],
                  AsW + i * 2048);
    }
#pragma unroll
    for (int i = 0; i < 4; ++i)
      gld_lds16(&Bt[(size_t)(ctile * 128 + brow[i]) * K + k0 + bgc[i] * 8],
                BsW + i * 2048);
    __syncthreads();  // drains vmcnt (DMA complete)
#pragma unroll
    for (int h = 0; h < 2; ++h) {
      bf16x8 af[2], bfr[4];
#pragma unroll
      for (int i = 0; i < 2; ++i) {
        int r = wr * 32 + i * 16 + l16;
        int cc = (h * 4 + quad) ^ (r & 7);
        af[i] = *(const bf16x8*)&As[r * 64 + cc * 8];
      }
#pragma unroll
      for (int j = 0; j < 4; ++j) {
        int n = wc * 64 + j * 16 + l16;
        int cc = (h * 4 + quad) ^ (n & 7);
        bfr[j] = *(const bf16x8*)&Bs[n * 64 + cc * 8];
      }
#pragma unroll
      for (int i = 0; i < 2; ++i)
#pragma unroll
        for (int j = 0; j < 4; ++j)
          acc[i][j] = __builtin_amdgcn_mfma_f32_16x16x32_bf16(af[i], bfr[j],
                                                              acc[i][j], 0, 0, 0);
    }
  }

  // C/D layout: col = lane&15, row = quad*4 + reg (m89/m91)
  const int crow0 = rtile * 64 + wr * 32 + quad * 4;
  const int ccol0 = ctile * 128 + wc * 64 + l16;
#pragma unroll
  for (int j = 0; j < 4; ++j) {
    const int col = ccol0 + j * 16;
    const float bv = biasf ? biasf[col] : 0.f;
#pragma unroll
    for (int i = 0; i < 2; ++i)
#pragma unroll
      for (int r = 0; r < 4; ++r) {
        bf16 o = (bf16)(acc[i][j][r] + bv);
        C[(size_t)(crow0 + i * 16 + r) * cstride + col] = *(u16*)&o;
      }
  }
}

// ---- prep2: TWc = TW1 @ Wemb^T via MFMA (blocks 0..7; C 512x128, stride 128)
//             bvec[n] = sum_m bemb[m] * TW1[n][m]  (blocks 8..9, bf16x8 dots)
__global__ __launch_bounds__(256) void prep2_kernel(
    const u16* __restrict__ node, const void* __restrict__ bemb,
    const u16* __restrict__ TW1, const u16* __restrict__ WembB,
    const void* __restrict__ Wemb, u16* __restrict__ TWc,
    float* __restrict__ bvec) {
  __shared__ __align__(16) u16 As[64 * 64];
  __shared__ __align__(16) u16 Bs[128 * 64];
  __shared__ float bembS[HH];
  const int bid = blockIdx.x, tid = threadIdx.x;
  const int f32in = probe_f32(node);
  if (bid < 8) {
    // Bt = Wemb (128 rows x K=512): raw input if already bf16, else the copy
    const u16* Bt = f32in ? WembB : (const u16*)Wemb;
    gemm_tile(TW1, HH, 0, Bt, nullptr, bid, 0, TWc, FN, As, Bs);
  } else {
    bembS[tid] = (float)cvt_elem(bemb, tid, f32in);
    bembS[256 + tid] = (float)cvt_elem(bemb, 256 + tid, f32in);
    __syncthreads();
    const int n = (bid - 8) * 256 + tid;  // 0..511
    float acc = 0.f;
#pragma unroll 8
    for (int m = 0; m < HH; m += 8) {
      bf16x8 w = *(const bf16x8*)&TW1[(size_t)n * HH + m];
#pragma unroll
      for (int j = 0; j < 8; ++j) acc += bembS[m + j] * (float)w[j];
    }
    bvec[n] = acc;
  }
}

// ---- G1: t = node @ TWc^T + bvec  (K=128, A maybe fp32)
__global__ __launch_bounds__(256) void g1_kernel(const u16* __restrict__ node,
                                                 const u16* __restrict__ TWc,
                                                 const float* __restrict__ bvec,
                                                 u16* __restrict__ C) {
  __shared__ __align__(16) u16 As[64 * 64];
  __shared__ __align__(16) u16 Bs[128 * 64];
  const int af32 = probe_f32(node);
  gemm_tile(node, FN, af32, TWc, bvec, blockIdx.x, blockIdx.y, C, HH, As, Bs);
}

// ---- mid GEMM: t = x @ W^T (no epilogue; bias/relu live in the next agg)
__global__ __launch_bounds__(256) void gemm_mid(const u16* __restrict__ A,
                                                const u16* __restrict__ Bt,
                                                u16* __restrict__ C) {
  __shared__ __align__(16) u16 As[64 * 64];
  __shared__ __align__(16) u16 Bs[128 * 64];
  gemm_tile(A, HH, 0, Bt, nullptr, blockIdx.x, blockIdx.y, C, HH, As, Bs);
}

// ---- agg + epilogue: y[i,:] = act( d[i]*( d[i]*t[i,:] + sum d[j]*t[j,:] ) + b )
// XCD-pinned column strips (R7): strip s read only by blocks with
// blockIdx%8 in {2s,2s+1} -> 2 MB of t resident per XCD-pair L2.
template <bool RELU, bool FINAL>
__global__ __launch_bounds__(256) void agg_kernel(
    const u16* __restrict__ t, const u32* __restrict__ idxw,
    const float* __restrict__ dis, const void* __restrict__ bias,
    const u16* __restrict__ nodeprobe, void* __restrict__ y) {
  const int i64 = probe_i64(idxw);
  const int f32io = probe_f32(nodeprobe);
  const int* idx = (const int*)idxw;
  const int b = blockIdx.x;
  const int strip = (b & 7) >> 1;          // 0..3, pinned to XCD pair
  const int grp = (b >> 3) * 2 + (b & 1);  // 0..511 node group
  const int wave = threadIdx.x >> 6, lane = threadIdx.x & 63;
  const int node = grp * 16 + wave * 4 + (lane >> 4);
  const int c0 = strip * 128 + (lane & 15) * 8;
  const float wi = dis[node];
  float acc[8];
  bf16x8 xs = *(const bf16x8*)&t[(size_t)node * HH + c0];
#pragma unroll
  for (int k = 0; k < 8; ++k) acc[k] = wi * wi * (float)xs[k];
#pragma unroll
  for (int e = 0; e < MM; ++e) {
    const int j = idx[(node * MM + e) << i64];
    if (j >= 0) {
      const float w = wi * dis[j];
      bf16x8 v = *(const bf16x8*)&t[(size_t)j * HH + c0];
#pragma unroll
      for (int k = 0; k < 8; ++k) acc[k] += w * (float)v[k];
    }
  }
  float bv[8];
  if (f32io) {
    f32x4 b0 = *(const f32x4*)&((const float*)bias)[c0];
    f32x4 b1 = *(const f32x4*)&((const float*)bias)[c0 + 4];
#pragma unroll
    for (int k = 0; k < 4; ++k) { bv[k] = b0[k]; bv[4 + k] = b1[k]; }
  } else {
    bf16x8 bb = *(const bf16x8*)&((const u16*)bias)[c0];
#pragma unroll
    for (int k = 0; k < 8; ++k) bv[k] = (float)bb[k];
  }
#pragma unroll
  for (int k = 0; k < 8; ++k) {
    acc[k] += bv[k];
    if (RELU) acc[k] = fmaxf(acc[k], 0.f);
  }
  if (FINAL && f32io) {
    float* O = (float*)y;
    f32x4 o0, o1;
#pragma unroll
    for (int k = 0; k < 4; ++k) { o0[k] = acc[k]; o1[k] = acc[4 + k]; }
    *(f32x4*)&O[(size_t)node * HH + c0] = o0;
    *(f32x4*)&O[(size_t)node * HH + c0 + 4] = o1;
  } else {
    bf16x8 o;
#pragma unroll
    for (int k = 0; k < 8; ++k) o[k] = (bf16)acc[k];
    *(bf16x8*)&((u16*)y)[(size_t)node * HH + c0] = o;
  }
}

extern "C" void kernel_launch(void* const* d_in, const int* in_sizes, int n_in,
                              void* d_out, int out_size, void* d_ws, size_t ws_size,
                              hipStream_t stream) {
  const u16* node = (const u16*)d_in[0];
  const u32* idxw = (const u32*)d_in[1];
  const void* Wemb = d_in[2];
  const void* bemb = d_in[3];
  const void* W1 = d_in[4];
  const void* b1 = d_in[5];
  const void* W2 = d_in[6];
  const void* b2 = d_in[7];
  const void* W3 = d_in[8];
  const void* b3 = d_in[9];

  char* p = (char*)d_ws;
  float* dis = (float*)p;   p += NN * sizeof(float);
  float* bvec = (float*)p;  p += HH * sizeof(float);
  u16* TWc = (u16*)p;       p += (size_t)HH * FN * 2;
  u16* WembB = (u16*)p;     p += (size_t)FN * HH * 2;
  u16* TW1 = (u16*)p;       p += (size_t)HH * HH * 2;
  u16* TW2 = (u16*)p;       p += (size_t)HH * HH * 2;
  u16* TW3 = (u16*)p;       p += (size_t)HH * HH * 2;
  u16* xA = (u16*)p;        // 8 MB GEMM-out buffer
  u16* xO = (u16*)d_out;    // d_out doubles as bf16 ping buffer

  prep1_kernel<<<832, 256, 0, stream>>>(node, idxw, Wemb, W1, W2, W3, dis, TW1,
                                        TW2, TW3, WembB);
  prep2_kernel<<<10, 256, 0, stream>>>(node, bemb, TW1, WembB, Wemb, TWc, bvec);
  g1_kernel<<<dim3(128, 4), 256, 0, stream>>>(node, TWc, bvec, xA);
  agg_kernel<true, false>
      <<<NN / 4, 256, 0, stream>>>(xA, idxw, dis, b1, node, xO);
  gemm_mid<<<dim3(128, 4), 256, 0, stream>>>(xO, TW2, xA);
  agg_kernel<true, false>
      <<<NN / 4, 256, 0, stream>>>(xA, idxw, dis, b2, node, xO);
  gemm_mid<<<dim3(128, 4), 256, 0, stream>>>(xO, TW3, xA);
  agg_kernel<false, true>
      <<<NN / 4, 256, 0, stream>>>(xA, idxw, dis, b3, node, d_out);
}